// Round 12
// baseline (1142.891 us; speedup 1.0000x reference)
//
#include <hip/hip_runtime.h>

#define F_IN 128
#define HID 64
#define CLS 32
#define BCAP 4096   // per-bucket capacity (128-node buckets, mean 2048 records)

typedef short v8s __attribute__((ext_vector_type(8)));
typedef float f4 __attribute__((ext_vector_type(4)));
typedef float f2 __attribute__((ext_vector_type(2)));

// ---- helpers ----
__device__ __forceinline__ float bflo(unsigned int w) { return __uint_as_float(w << 16); }
__device__ __forceinline__ float bfhi(unsigned int w) { return __uint_as_float(w & 0xFFFF0000u); }
__device__ __forceinline__ unsigned short f2bf(float f) {
    unsigned int u = __float_as_uint(f);
    u += 0x7FFFu + ((u >> 16) & 1u);
    return (unsigned short)(u >> 16);
}
__device__ __forceinline__ unsigned int pack2(float lo, float hi) {
    unsigned int r;
    asm("v_cvt_pk_bf16_f32 %0, %1, %2" : "=v"(r) : "v"(lo), "v"(hi));
    return r;
}
__device__ __forceinline__ unsigned char f2fp8(float v) {
    return (unsigned char)(__builtin_amdgcn_cvt_pk_fp8_f32(v, v, 0, false) & 0xFF);
}

// 16 fp8 (uint4) * dv accumulated into LDS f32
__device__ __forceinline__ void acc16(float* ap, uint4 w, float dv) {
    f2 D = {dv, dv};
    f2 t;
    t = __builtin_amdgcn_cvt_pk_f32_fp8(w.x, false) * D;
    atomicAdd(&ap[0], t.x); atomicAdd(&ap[1], t.y);
    t = __builtin_amdgcn_cvt_pk_f32_fp8(w.x, true) * D;
    atomicAdd(&ap[2], t.x); atomicAdd(&ap[3], t.y);
    t = __builtin_amdgcn_cvt_pk_f32_fp8(w.y, false) * D;
    atomicAdd(&ap[4], t.x); atomicAdd(&ap[5], t.y);
    t = __builtin_amdgcn_cvt_pk_f32_fp8(w.y, true) * D;
    atomicAdd(&ap[6], t.x); atomicAdd(&ap[7], t.y);
    t = __builtin_amdgcn_cvt_pk_f32_fp8(w.z, false) * D;
    atomicAdd(&ap[8], t.x); atomicAdd(&ap[9], t.y);
    t = __builtin_amdgcn_cvt_pk_f32_fp8(w.z, true) * D;
    atomicAdd(&ap[10], t.x); atomicAdd(&ap[11], t.y);
    t = __builtin_amdgcn_cvt_pk_f32_fp8(w.w, false) * D;
    atomicAdd(&ap[12], t.x); atomicAdd(&ap[13], t.y);
    t = __builtin_amdgcn_cvt_pk_f32_fp8(w.w, true) * D;
    atomicAdd(&ap[14], t.x); atomicAdd(&ap[15], t.y);
}

// 8 bf16 (uint4) accumulated into LDS f32
__device__ __forceinline__ void acc8(float* ap, uint4 w) {
    atomicAdd(&ap[0], bflo(w.x)); atomicAdd(&ap[1], bfhi(w.x));
    atomicAdd(&ap[2], bflo(w.y)); atomicAdd(&ap[3], bfhi(w.y));
    atomicAdd(&ap[4], bflo(w.z)); atomicAdd(&ap[5], bfhi(w.z));
    atomicAdd(&ap[6], bflo(w.w)); atomicAdd(&ap[7], bfhi(w.w));
}

// ============ K1: FRONT = bucket-scatter || GEMM1 (unchanged, proven ~40us) ============
__global__ __launch_bounds__(256) void k_front(const int* __restrict__ src,
                                               const int* __restrict__ dst,
                                               int* __restrict__ bC,
                                               int* __restrict__ bucketed,
                                               const float* __restrict__ x,
                                               const float* __restrict__ W1,
                                               unsigned char* __restrict__ y,
                                               int E, int nb, int n, int sB) {
    __shared__ union {
        struct { int h[1024]; int chunk[1024]; } sc;
        unsigned short w1[HID * 136];
    } S;
    int tid = threadIdx.x;
    int bid = blockIdx.x;

    if (bid < sB) {
        for (int i = tid; i < nb; i += 256) S.sc.h[i] = 0;
        __syncthreads();
        int e0 = bid << 12;
        int myRec[16], myB[16], myRank[16];
#pragma unroll
        for (int k = 0; k < 16; ++k) {
            int e = e0 + k * 256 + tid;
            if (e < E) {
                int d = dst[e];
                myB[k] = d >> 7;
                myRec[k] = src[e] | ((d & 127) << 17);
                myRank[k] = atomicAdd(&S.sc.h[myB[k]], 1);
            } else {
                myB[k] = -1;
            }
        }
        __syncthreads();
        for (int i = tid; i < nb; i += 256)
            S.sc.chunk[i] = S.sc.h[i] ? (i * BCAP + atomicAdd(&bC[i], S.sc.h[i])) : 0;
        __syncthreads();
#pragma unroll
        for (int k = 0; k < 16; ++k)
            if (myB[k] >= 0) bucketed[S.sc.chunk[myB[k]] + myRank[k]] = myRec[k];
    } else {
        for (int i = tid; i < F_IN * HID; i += 256) {
            int k = i >> 6, nn = i & 63;
            S.w1[nn * 136 + k] = f2bf(W1[i]);
        }
        __syncthreads();
        int lane = tid & 63;
        int quad = lane >> 4, c = lane & 15;
        int nstripes = (n + 15) >> 4;
        int stripe = (bid - sB) * 4 + (tid >> 6);
        if (stripe >= nstripes) return;
        int row0 = stripe << 4;

        f4 acc[4] = {};
        union { unsigned int u[4]; v8s v; } au;
#pragma unroll
        for (int ks = 0; ks < 4; ++ks) {
            int k0 = ks * 32 + quad * 8;
            int row = row0 + c;
            if (row >= n) row = n - 1;
            const float* xp = x + (size_t)row * F_IN + k0;
            float4 lo = *(const float4*)xp;
            float4 hi = *(const float4*)(xp + 4);
            au.u[0] = pack2(lo.x, lo.y);
            au.u[1] = pack2(lo.z, lo.w);
            au.u[2] = pack2(hi.x, hi.y);
            au.u[3] = pack2(hi.z, hi.w);
            v8s a = au.v;
#pragma unroll
            for (int nt = 0; nt < 4; ++nt) {
                v8s bb = *(const v8s*)&S.w1[(nt * 16 + c) * 136 + k0];
                acc[nt] = __builtin_amdgcn_mfma_f32_16x16x32_bf16(a, bb, acc[nt], 0, 0, 0);
            }
        }
#pragma unroll
        for (int reg = 0; reg < 4; ++reg) {
            int row = row0 + quad * 4 + reg;
            if (row < n) {
#pragma unroll
                for (int nt = 0; nt < 4; ++nt)
                    y[(size_t)row * HID + nt * 16 + c] = f2fp8(acc[nt][reg]);
            }
        }
    }
}

// ============ K2: per-bucket degree count -> dinv (no ordering, no csr) ============
__global__ __launch_bounds__(256) void k_cnt(const int* __restrict__ bC,
                                             const int* __restrict__ bucketed,
                                             float* __restrict__ dinv, int n) {
    __shared__ int cnt[128];
    int tid = threadIdx.x, b = blockIdx.x;
    if (tid < 128) cnt[tid] = 0;
    __syncthreads();
    int nrec = bC[b];
    if (nrec > BCAP) nrec = BCAP;
    int p0 = b * BCAP;
    for (int p = tid; p < nrec; p += 256) atomicAdd(&cnt[bucketed[p0 + p] >> 17], 1);
    __syncthreads();
    if (tid < 128) {
        int node = (b << 7) + tid;
        if (node < n) dinv[node] = rsqrtf((float)(cnt[tid] + 1));
    }
}

// ============ K3: layer-1 aggregation, EDGE-PARALLEL per bucket ============
// 4 lanes/record, LDS f32 atomic accumulate (dinv[src]-scaled fp8 rows), then
// self + bias + relu -> bf16 tile (aliased) -> W2 MFMA -> y2 (pre-normalized).
__global__ __launch_bounds__(256) void k_agg1(const int* __restrict__ bC,
                                              const int* __restrict__ bucketed,
                                              const unsigned char* __restrict__ xw8,
                                              const float* __restrict__ b1,
                                              const float* __restrict__ W2,
                                              const float* __restrict__ dinv,
                                              unsigned short* __restrict__ y2, int n) {
    __shared__ union {
        float accf[128 * 72];          // f32 accumulate phase (stride 72 spreads banks)
        unsigned short hb[128 * 72];   // bf16 relu(h) tile phase (aliased after barrier)
    } A;
    __shared__ unsigned short Wt[CLS * 72];
    int tid = threadIdx.x;
    int b = blockIdx.x;
    for (int i = tid; i < HID * CLS; i += 256) {
        int k = i >> 5, nn = i & 31;
        Wt[nn * 72 + k] = f2bf(W2[i]);
    }
    for (int i = tid; i < 128 * 72; i += 256) A.accf[i] = 0.f;
    __syncthreads();

    int nrec = bC[b];
    if (nrec > BCAP) nrec = BCAP;
    int p0 = b * BCAP;
    int l = tid & 3;   // 16B slice of the 64B fp8 row
    for (int p = (tid >> 2); p < nrec; p += 128) {
        int rec0 = bucketed[p0 + p];
        int pB = p + 64;
        int rec1 = (pB < nrec) ? bucketed[p0 + pB] : -1;
        int s0 = rec0 & 0x1FFFF, loc0 = rec0 >> 17;
        float dv0 = dinv[s0];
        uint4 w0 = *(const uint4*)(xw8 + (size_t)s0 * HID + l * 16);
        if (rec1 >= 0) {
            int s1 = rec1 & 0x1FFFF, loc1 = rec1 >> 17;
            float dv1 = dinv[s1];
            uint4 w1 = *(const uint4*)(xw8 + (size_t)s1 * HID + l * 16);
            acc16(&A.accf[loc0 * 72 + l * 16], w0, dv0);
            acc16(&A.accf[loc1 * 72 + l * 16], w1, dv1);
        } else {
            acc16(&A.accf[loc0 * 72 + l * 16], w0, dv0);
        }
    }
    __syncthreads();

    // ---- epilogue: 2 threads/node, 32 cols each: h = relu((acc + dv*self)*dv + b1) ----
    int node0 = b << 7;
    int g = tid >> 1, l2 = tid & 1;
    int node = node0 + g;
    bool alive = node < n;
    unsigned int hp4[16];
    if (alive) {
        float dv = dinv[node];
        const float* ap = &A.accf[g * 72 + l2 * 32];
        float av[32];
#pragma unroll
        for (int q = 0; q < 8; ++q) *(float4*)&av[q * 4] = *(const float4*)(ap + q * 4);
        uint4 sv0 = *(const uint4*)(xw8 + (size_t)node * HID + l2 * 32);
        uint4 sv1 = *(const uint4*)(xw8 + (size_t)node * HID + l2 * 32 + 16);
        unsigned int su[8] = {sv0.x, sv0.y, sv0.z, sv0.w, sv1.x, sv1.y, sv1.z, sv1.w};
        float bias[32];
#pragma unroll
        for (int q = 0; q < 8; ++q)
            *(float4*)&bias[q * 4] = *(const float4*)(b1 + l2 * 32 + q * 4);
        float hv[32];
#pragma unroll
        for (int q = 0; q < 8; ++q) {
            f2 lo = __builtin_amdgcn_cvt_pk_f32_fp8(su[q], false);
            f2 hi = __builtin_amdgcn_cvt_pk_f32_fp8(su[q], true);
            hv[q * 4 + 0] = lo.x;
            hv[q * 4 + 1] = lo.y;
            hv[q * 4 + 2] = hi.x;
            hv[q * 4 + 3] = hi.y;
        }
#pragma unroll
        for (int j = 0; j < 32; ++j)
            hv[j] = fmaxf((av[j] + dv * hv[j]) * dv + bias[j], 0.f);
#pragma unroll
        for (int k = 0; k < 16; ++k) hp4[k] = pack2(hv[2 * k], hv[2 * k + 1]);
    }
    __syncthreads();   // all acc reads done before bf16 overwrite
    if (alive) {
        uint4* hbp = (uint4*)&A.hb[g * 72 + l2 * 32];   // byte off = g*144 + l2*64, 16B aligned
        hbp[0] = make_uint4(hp4[0], hp4[1], hp4[2], hp4[3]);
        hbp[1] = make_uint4(hp4[4], hp4[5], hp4[6], hp4[7]);
        hbp[2] = make_uint4(hp4[8], hp4[9], hp4[10], hp4[11]);
        hbp[3] = make_uint4(hp4[12], hp4[13], hp4[14], hp4[15]);
    }
    __syncthreads();

    // ---- MFMA: 8 row-tiles x 2 col-tiles over Hb[128][64], 4 waves x 4 tiles ----
    int wv = tid >> 6, lane = tid & 63, quad = lane >> 4, c = lane & 15;
    int ct = wv & 1;
    for (int rt = (wv >> 1); rt < 8; rt += 2) {
        f4 acc = {};
#pragma unroll
        for (int ks = 0; ks < 2; ++ks) {
            int k0 = ks * 32 + quad * 8;
            v8s aF = *(const v8s*)&A.hb[(rt * 16 + c) * 72 + k0];
            v8s bF = *(const v8s*)&Wt[(ct * 16 + c) * 72 + k0];
            acc = __builtin_amdgcn_mfma_f32_16x16x32_bf16(aF, bF, acc, 0, 0, 0);
        }
#pragma unroll
        for (int reg = 0; reg < 4; ++reg) {
            int row = node0 + rt * 16 + quad * 4 + reg;
            if (row < n)
                y2[(size_t)row * CLS + ct * 16 + c] = f2bf(acc[reg] * dinv[row]);
        }
    }
}

// ============ K4: layer-2 aggregation, EDGE-PARALLEL per bucket + log_softmax ============
// y2 rows are pre-normalized (dinv[src] folded in) -> pure LDS f32 atomic add.
__global__ __launch_bounds__(256) void k_agg2(const int* __restrict__ bC,
                                              const int* __restrict__ bucketed,
                                              const unsigned short* __restrict__ y2,
                                              const float* __restrict__ b2,
                                              const float* __restrict__ dinv,
                                              float* __restrict__ out, int n) {
    __shared__ float acc[128 * 36];   // stride 36 spreads banks; 18.4 KB
    int tid = threadIdx.x;
    int b = blockIdx.x;
    for (int i = tid; i < 128 * 36; i += 256) acc[i] = 0.f;
    __syncthreads();

    int nrec = bC[b];
    if (nrec > BCAP) nrec = BCAP;
    int p0 = b * BCAP;
    int l = tid & 3;   // 16B slice (8 bf16) of the 64B row
    for (int p = (tid >> 2); p < nrec; p += 128) {
        int rec0 = bucketed[p0 + p];
        int pB = p + 64;
        int rec1 = (pB < nrec) ? bucketed[p0 + pB] : -1;
        int s0 = rec0 & 0x1FFFF, loc0 = rec0 >> 17;
        uint4 w0 = *(const uint4*)(y2 + (size_t)s0 * CLS + l * 8);
        if (rec1 >= 0) {
            int s1 = rec1 & 0x1FFFF, loc1 = rec1 >> 17;
            uint4 w1 = *(const uint4*)(y2 + (size_t)s1 * CLS + l * 8);
            acc8(&acc[loc0 * 36 + l * 8], w0);
            acc8(&acc[loc1 * 36 + l * 8], w1);
        } else {
            acc8(&acc[loc0 * 36 + l * 8], w0);
        }
    }
    __syncthreads();

    // ---- epilogue: 2 threads/node x 16 cols; v = (acc + self)*dd + b2; log_softmax ----
    int node = (b << 7) + (tid >> 1);
    int l2 = tid & 1;
    if (node >= n) return;
    float dd = dinv[node];
    const float* ap = &acc[(tid >> 1) * 36 + l2 * 16];
    float av[16];
#pragma unroll
    for (int q = 0; q < 4; ++q) *(float4*)&av[q * 4] = *(const float4*)(ap + q * 4);
    uint4 sv0 = *(const uint4*)(y2 + (size_t)node * CLS + l2 * 16);
    uint4 sv1 = *(const uint4*)(y2 + (size_t)node * CLS + l2 * 16 + 8);
    unsigned int su[8] = {sv0.x, sv0.y, sv0.z, sv0.w, sv1.x, sv1.y, sv1.z, sv1.w};
    float bias[16];
#pragma unroll
    for (int q = 0; q < 4; ++q)
        *(float4*)&bias[q * 4] = *(const float4*)(b2 + l2 * 16 + q * 4);
    float v[16];
#pragma unroll
    for (int q = 0; q < 8; ++q) {
        v[q * 2 + 0] = (av[q * 2 + 0] + bflo(su[q])) * dd + bias[q * 2 + 0];
        v[q * 2 + 1] = (av[q * 2 + 1] + bfhi(su[q])) * dd + bias[q * 2 + 1];
    }
    float m = v[0];
#pragma unroll
    for (int j = 1; j < 16; ++j) m = fmaxf(m, v[j]);
    m = fmaxf(m, __shfl_xor(m, 1));
    float s = 0.f;
#pragma unroll
    for (int j = 0; j < 16; ++j) s += __expf(v[j] - m);
    s += __shfl_xor(s, 1);
    float ls = m + __logf(s);
    float* op = out + (size_t)node * CLS + l2 * 16;
#pragma unroll
    for (int q = 0; q < 4; ++q) {
        float4 o;
        o.x = v[q * 4 + 0] - ls;
        o.y = v[q * 4 + 1] - ls;
        o.z = v[q * 4 + 2] - ls;
        o.w = v[q * 4 + 3] - ls;
        *(float4*)(op + q * 4) = o;
    }
}

extern "C" void kernel_launch(void* const* d_in, const int* in_sizes, int n_in,
                              void* d_out, int out_size, void* d_ws, size_t ws_size,
                              hipStream_t stream) {
    const float* x  = (const float*)d_in[0];
    const int* edge = (const int*)d_in[1];
    const float* W1 = (const float*)d_in[2];
    const float* b1 = (const float*)d_in[3];
    const float* W2 = (const float*)d_in[4];
    const float* b2 = (const float*)d_in[5];
    float* out = (float*)d_out;

    int N = in_sizes[0] / F_IN;
    int E = in_sizes[1] / 2;
    const int* src = edge;
    const int* dst = edge + E;
    int NB = (N + 127) >> 7;   // 782 buckets of 128 nodes

    // workspace layout
    float* dinv    = (float*)d_ws;                        // N f32
    int* bC        = (int*)(dinv + N);                    // 1024 (delta cursors)
    int* bucketed  = bC + 1024;                           // NB*BCAP
    unsigned char* bufA = (unsigned char*)(bucketed + (size_t)NB * BCAP);  // N*64 B fp8 xW1
    unsigned short* y2  = (unsigned short*)(bufA + (size_t)N * HID);       // N*32 bf16 (normalized)

    // zero delta-cursors (3.1 KB)
    (void)hipMemsetAsync(bC, 0, (size_t)NB * sizeof(int), stream);

    int sB = (E + 4095) / 4096;               // scatter blocks (one 4096-edge chunk each)
    int nstripes16 = (N + 15) >> 4;
    int gB = (nstripes16 + 3) / 4;            // gemm1 blocks (4 stripes each)

    // ---- K1: scatter || gemm1 (independent, static block split) ----
    k_front<<<sB + gB, 256, 0, stream>>>(src, dst, bC, bucketed, x, W1, bufA, E, NB, N, sB);

    // ---- K2: degree count -> dinv ----
    k_cnt<<<NB, 256, 0, stream>>>(bC, bucketed, dinv, N);

    // ---- K3: layer-1 edge-parallel aggregation + bias/relu + W2 MFMA -> y2 ----
    k_agg1<<<NB, 256, 0, stream>>>(bC, bucketed, bufA, b1, W2, dinv, y2, N);

    // ---- K4: layer-2 edge-parallel aggregation + log_softmax ----
    k_agg2<<<NB, 256, 0, stream>>>(bC, bucketed, y2, b2, dinv, out, N);
}

// Round 13
// 187.589 us; speedup vs baseline: 6.0925x; 6.0925x over previous
//
#include <hip/hip_runtime.h>

#define F_IN 128
#define HID 64
#define CLS 32
#define BCAP 4096   // per-bucket capacity (128-node buckets, mean 2048 records)

typedef short v8s __attribute__((ext_vector_type(8)));
typedef float f4 __attribute__((ext_vector_type(4)));
typedef float f2 __attribute__((ext_vector_type(2)));

// ---- helpers ----
__device__ __forceinline__ float bflo(unsigned int w) { return __uint_as_float(w << 16); }
__device__ __forceinline__ float bfhi(unsigned int w) { return __uint_as_float(w & 0xFFFF0000u); }
__device__ __forceinline__ unsigned short f2bf(float f) {
    unsigned int u = __float_as_uint(f);
    u += 0x7FFFu + ((u >> 16) & 1u);
    return (unsigned short)(u >> 16);
}
__device__ __forceinline__ unsigned int pack2(float lo, float hi) {
    unsigned int r;
    asm("v_cvt_pk_bf16_f32 %0, %1, %2" : "=v"(r) : "v"(lo), "v"(hi));
    return r;
}
__device__ __forceinline__ unsigned char f2fp8(float v) {
    return (unsigned char)(__builtin_amdgcn_cvt_pk_fp8_f32(v, v, 0, false) & 0xFF);
}

// ============ K1: FRONT = bucket-scatter || GEMM1 (round-5 proven, ~42us) ============
__global__ __launch_bounds__(256) void k_front(const int* __restrict__ src,
                                               const int* __restrict__ dst,
                                               int* __restrict__ bC,
                                               int* __restrict__ bucketed,
                                               const float* __restrict__ x,
                                               const float* __restrict__ W1,
                                               unsigned char* __restrict__ y,
                                               int E, int nb, int n, int sB) {
    __shared__ union {
        struct { int h[1024]; int chunk[1024]; } sc;
        unsigned short w1[HID * 136];
    } S;
    int tid = threadIdx.x;
    int bid = blockIdx.x;

    if (bid < sB) {
        for (int i = tid; i < nb; i += 256) S.sc.h[i] = 0;
        __syncthreads();
        int e0 = bid << 12;
        int myRec[16], myB[16], myRank[16];
#pragma unroll
        for (int k = 0; k < 16; ++k) {
            int e = e0 + k * 256 + tid;
            if (e < E) {
                int d = dst[e];
                myB[k] = d >> 7;
                myRec[k] = src[e] | ((d & 127) << 17);
                myRank[k] = atomicAdd(&S.sc.h[myB[k]], 1);
            } else {
                myB[k] = -1;
            }
        }
        __syncthreads();
        for (int i = tid; i < nb; i += 256)
            S.sc.chunk[i] = S.sc.h[i] ? (i * BCAP + atomicAdd(&bC[i], S.sc.h[i])) : 0;
        __syncthreads();
#pragma unroll
        for (int k = 0; k < 16; ++k)
            if (myB[k] >= 0) bucketed[S.sc.chunk[myB[k]] + myRank[k]] = myRec[k];
    } else {
        for (int i = tid; i < F_IN * HID; i += 256) {
            int k = i >> 6, nn = i & 63;
            S.w1[nn * 136 + k] = f2bf(W1[i]);
        }
        __syncthreads();
        int lane = tid & 63;
        int quad = lane >> 4, c = lane & 15;
        int nstripes = (n + 15) >> 4;
        int stripe = (bid - sB) * 4 + (tid >> 6);
        if (stripe >= nstripes) return;
        int row0 = stripe << 4;

        f4 acc[4] = {};
        union { unsigned int u[4]; v8s v; } au;
#pragma unroll
        for (int ks = 0; ks < 4; ++ks) {
            int k0 = ks * 32 + quad * 8;
            int row = row0 + c;
            if (row >= n) row = n - 1;
            const float* xp = x + (size_t)row * F_IN + k0;
            float4 lo = *(const float4*)xp;
            float4 hi = *(const float4*)(xp + 4);
            au.u[0] = pack2(lo.x, lo.y);
            au.u[1] = pack2(lo.z, lo.w);
            au.u[2] = pack2(hi.x, hi.y);
            au.u[3] = pack2(hi.z, hi.w);
            v8s a = au.v;
#pragma unroll
            for (int nt = 0; nt < 4; ++nt) {
                v8s bb = *(const v8s*)&S.w1[(nt * 16 + c) * 136 + k0];
                acc[nt] = __builtin_amdgcn_mfma_f32_16x16x32_bf16(a, bb, acc[nt], 0, 0, 0);
            }
        }
#pragma unroll
        for (int reg = 0; reg < 4; ++reg) {
            int row = row0 + quad * 4 + reg;
            if (row < n) {
#pragma unroll
                for (int nt = 0; nt < 4; ++nt)
                    y[(size_t)row * HID + nt * 16 + c] = f2fp8(acc[nt][reg]);
            }
        }
    }
}

// ============ K2: per-bucket degree count -> dinv (needed globally by k_g64) ============
__global__ __launch_bounds__(256) void k_cnt(const int* __restrict__ bC,
                                             const int* __restrict__ bucketed,
                                             float* __restrict__ dinv, int n) {
    __shared__ int cnt[128];
    int tid = threadIdx.x, b = blockIdx.x;
    if (tid < 128) cnt[tid] = 0;
    __syncthreads();
    int nrec = bC[b];
    if (nrec > BCAP) nrec = BCAP;
    int p0 = b * BCAP;
    for (int p = tid; p < nrec; p += 256) atomicAdd(&cnt[bucketed[p0 + p] >> 17], 1);
    __syncthreads();
    if (tid < 128) {
        int node = (b << 7) + tid;
        if (node < n) dinv[node] = rsqrtf((float)(cnt[tid] + 1));
    }
}

// ============ K3: per-bucket LDS-order build + gather64 + bias/relu + W2 MFMA -> y2 ====
// 512 thr, block = 1 bucket (128 nodes). Build: cnt->scan->lidx[4096] in LDS (k_csr
// pattern, LDS destination -> index reads during gather are LDS, not L2).
// Gather: 4 lanes/node, uint4 (16B) fp8 row slices, per-edge dinv[src] FMA.
__global__ __launch_bounds__(512) void k_g64(const int* __restrict__ bC,
                                             const int* __restrict__ bucketed,
                                             const unsigned char* __restrict__ xw8,
                                             const float* __restrict__ b1,
                                             const float* __restrict__ W2,
                                             const float* __restrict__ dinv,
                                             unsigned short* __restrict__ y2, int n) {
    __shared__ int lidx[BCAP];                 // 16 KB
    __shared__ int cnt[128], sS[128], baseL[128];
    __shared__ unsigned short Wt[CLS * 72];    // 4.5 KB
    __shared__ unsigned short Hl[128 * 72];    // 18 KB
    int tid = threadIdx.x, b = blockIdx.x;
    int node0 = b << 7;

    for (int i = tid; i < HID * CLS; i += 512) {
        int k = i >> 5, nn = i & 31;
        Wt[nn * 72 + k] = f2bf(W2[i]);
    }
    if (tid < 128) cnt[tid] = 0;
    __syncthreads();
    int nrec = bC[b];
    if (nrec > BCAP) nrec = BCAP;
    int p0 = b * BCAP;
    int rec[8], rnk[8];
#pragma unroll
    for (int k = 0; k < 8; ++k) {
        int p = tid + (k << 9);
        if (p < nrec) {
            int r = bucketed[p0 + p];
            rec[k] = r;
            rnk[k] = atomicAdd(&cnt[r >> 17], 1);
        } else {
            rec[k] = -1;
        }
    }
    __syncthreads();
    int v = 0;
    if (tid < 128) { v = cnt[tid]; sS[tid] = v; }
    __syncthreads();
    for (int off = 1; off < 128; off <<= 1) {
        int t = (tid >= off && tid < 128) ? sS[tid - off] : 0;
        __syncthreads();
        if (tid < 128) sS[tid] += t;
        __syncthreads();
    }
    if (tid < 128) baseL[tid] = sS[tid] - v;
    __syncthreads();
#pragma unroll
    for (int k = 0; k < 8; ++k)
        if (rec[k] >= 0) lidx[baseL[rec[k] >> 17] + rnk[k]] = rec[k] & 0x1FFFF;
    __syncthreads();

    // ---- gather: group of 4 lanes per node; lane l covers fp8 cols 16l..16l+15 ----
    int g = tid >> 2, l = tid & 3;
    int node = node0 + g;
    if (node < n) {
        int cv = cnt[g];
        float dd = rsqrtf((float)(cv + 1));
        int q = baseL[g], q1 = baseL[g] + cv;
        uint4 sw = *(const uint4*)(xw8 + (size_t)node * HID + l * 16);

        f2 a0 = {0.f, 0.f}, a1 = a0, a2 = a0, a3 = a0, a4 = a0, a5 = a0, a6 = a0, a7 = a0;
        f2 c0 = a0, c1 = a0, c2 = a0, c3 = a0, c4 = a0, c5 = a0, c6 = a0, c7 = a0;
        for (; q + 1 < q1; q += 2) {
            int s0 = lidx[q], s1 = lidx[q + 1];
            float dv0 = dinv[s0], dv1 = dinv[s1];
            uint4 w0 = *(const uint4*)(xw8 + (size_t)s0 * HID + l * 16);
            uint4 w1 = *(const uint4*)(xw8 + (size_t)s1 * HID + l * 16);
            f2 D0 = {dv0, dv0}, D1 = {dv1, dv1};
            a0 += __builtin_amdgcn_cvt_pk_f32_fp8(w0.x, false) * D0;
            a1 += __builtin_amdgcn_cvt_pk_f32_fp8(w0.x, true) * D0;
            a2 += __builtin_amdgcn_cvt_pk_f32_fp8(w0.y, false) * D0;
            a3 += __builtin_amdgcn_cvt_pk_f32_fp8(w0.y, true) * D0;
            a4 += __builtin_amdgcn_cvt_pk_f32_fp8(w0.z, false) * D0;
            a5 += __builtin_amdgcn_cvt_pk_f32_fp8(w0.z, true) * D0;
            a6 += __builtin_amdgcn_cvt_pk_f32_fp8(w0.w, false) * D0;
            a7 += __builtin_amdgcn_cvt_pk_f32_fp8(w0.w, true) * D0;
            c0 += __builtin_amdgcn_cvt_pk_f32_fp8(w1.x, false) * D1;
            c1 += __builtin_amdgcn_cvt_pk_f32_fp8(w1.x, true) * D1;
            c2 += __builtin_amdgcn_cvt_pk_f32_fp8(w1.y, false) * D1;
            c3 += __builtin_amdgcn_cvt_pk_f32_fp8(w1.y, true) * D1;
            c4 += __builtin_amdgcn_cvt_pk_f32_fp8(w1.z, false) * D1;
            c5 += __builtin_amdgcn_cvt_pk_f32_fp8(w1.z, true) * D1;
            c6 += __builtin_amdgcn_cvt_pk_f32_fp8(w1.w, false) * D1;
            c7 += __builtin_amdgcn_cvt_pk_f32_fp8(w1.w, true) * D1;
        }
        if (q < q1) {
            int s0 = lidx[q];
            float dv0 = dinv[s0];
            uint4 w0 = *(const uint4*)(xw8 + (size_t)s0 * HID + l * 16);
            f2 D0 = {dv0, dv0};
            a0 += __builtin_amdgcn_cvt_pk_f32_fp8(w0.x, false) * D0;
            a1 += __builtin_amdgcn_cvt_pk_f32_fp8(w0.x, true) * D0;
            a2 += __builtin_amdgcn_cvt_pk_f32_fp8(w0.y, false) * D0;
            a3 += __builtin_amdgcn_cvt_pk_f32_fp8(w0.y, true) * D0;
            a4 += __builtin_amdgcn_cvt_pk_f32_fp8(w0.z, false) * D0;
            a5 += __builtin_amdgcn_cvt_pk_f32_fp8(w0.z, true) * D0;
            a6 += __builtin_amdgcn_cvt_pk_f32_fp8(w0.w, false) * D0;
            a7 += __builtin_amdgcn_cvt_pk_f32_fp8(w0.w, true) * D0;
        }
        a0 += c0; a1 += c1; a2 += c2; a3 += c3;
        a4 += c4; a5 += c5; a6 += c6; a7 += c7;
        f2 DS = {dd, dd};
        a0 += __builtin_amdgcn_cvt_pk_f32_fp8(sw.x, false) * DS;
        a1 += __builtin_amdgcn_cvt_pk_f32_fp8(sw.x, true) * DS;
        a2 += __builtin_amdgcn_cvt_pk_f32_fp8(sw.y, false) * DS;
        a3 += __builtin_amdgcn_cvt_pk_f32_fp8(sw.y, true) * DS;
        a4 += __builtin_amdgcn_cvt_pk_f32_fp8(sw.z, false) * DS;
        a5 += __builtin_amdgcn_cvt_pk_f32_fp8(sw.z, true) * DS;
        a6 += __builtin_amdgcn_cvt_pk_f32_fp8(sw.w, false) * DS;
        a7 += __builtin_amdgcn_cvt_pk_f32_fp8(sw.w, true) * DS;

        // h = relu(a*dd + b1), 16 cols per lane
        float4 bb0 = *(const float4*)(b1 + l * 16);
        float4 bb1 = *(const float4*)(b1 + l * 16 + 4);
        float4 bb2 = *(const float4*)(b1 + l * 16 + 8);
        float4 bb3 = *(const float4*)(b1 + l * 16 + 12);
        float h0  = fmaxf(a0.x * dd + bb0.x, 0.f), h1  = fmaxf(a0.y * dd + bb0.y, 0.f);
        float h2  = fmaxf(a1.x * dd + bb0.z, 0.f), h3  = fmaxf(a1.y * dd + bb0.w, 0.f);
        float h4  = fmaxf(a2.x * dd + bb1.x, 0.f), h5  = fmaxf(a2.y * dd + bb1.y, 0.f);
        float h6  = fmaxf(a3.x * dd + bb1.z, 0.f), h7  = fmaxf(a3.y * dd + bb1.w, 0.f);
        float h8  = fmaxf(a4.x * dd + bb2.x, 0.f), h9  = fmaxf(a4.y * dd + bb2.y, 0.f);
        float h10 = fmaxf(a5.x * dd + bb2.z, 0.f), h11 = fmaxf(a5.y * dd + bb2.w, 0.f);
        float h12 = fmaxf(a6.x * dd + bb3.x, 0.f), h13 = fmaxf(a6.y * dd + bb3.y, 0.f);
        float h14 = fmaxf(a7.x * dd + bb3.z, 0.f), h15 = fmaxf(a7.y * dd + bb3.w, 0.f);
        uint4* hbp = (uint4*)&Hl[g * 72 + l * 16];    // byte off = g*144 + l*32, 16B aligned
        hbp[0] = make_uint4(pack2(h0, h1), pack2(h2, h3), pack2(h4, h5), pack2(h6, h7));
        hbp[1] = make_uint4(pack2(h8, h9), pack2(h10, h11), pack2(h12, h13), pack2(h14, h15));
    }
    __syncthreads();

    // ---- MFMA: Hb[128][64] @ W2[64][32]: 8 row-tiles x 2 col-tiles, 8 waves x 2 tiles ----
    int wv = tid >> 6, lane = tid & 63, quad = lane >> 4, c = lane & 15;
    int ct = wv & 1;
    int rt0 = wv >> 1;
#pragma unroll
    for (int rr = 0; rr < 2; ++rr) {
        int rt = rt0 + rr * 4;
        f4 acc = {};
#pragma unroll
        for (int ks = 0; ks < 2; ++ks) {
            int k0 = ks * 32 + quad * 8;
            v8s aF = *(const v8s*)&Hl[(rt * 16 + c) * 72 + k0];
            v8s bF = *(const v8s*)&Wt[(ct * 16 + c) * 72 + k0];
            acc = __builtin_amdgcn_mfma_f32_16x16x32_bf16(aF, bF, acc, 0, 0, 0);
        }
#pragma unroll
        for (int reg = 0; reg < 4; ++reg) {
            int rl = rt * 16 + quad * 4 + reg;
            int row = node0 + rl;
            if (row < n) {
                float dd2 = rsqrtf((float)(cnt[rl] + 1));
                y2[(size_t)row * CLS + ct * 16 + c] = f2bf(acc[reg] * dd2);
            }
        }
    }
}

// ============ K4: per-bucket LDS-order build + gather32 + log_softmax ============
// 512 thr, block = 1 bucket. y2 rows pre-normalized -> pure add; 4 lanes/node (8 bf16 each).
__global__ __launch_bounds__(512) void k_g32(const int* __restrict__ bC,
                                             const int* __restrict__ bucketed,
                                             const unsigned short* __restrict__ y2,
                                             const float* __restrict__ b2,
                                             float* __restrict__ out, int n) {
    __shared__ int lidx[BCAP];
    __shared__ int cnt[128], sS[128], baseL[128];
    int tid = threadIdx.x, b = blockIdx.x;
    int node0 = b << 7;
    if (tid < 128) cnt[tid] = 0;
    __syncthreads();
    int nrec = bC[b];
    if (nrec > BCAP) nrec = BCAP;
    int p0 = b * BCAP;
    int rec[8], rnk[8];
#pragma unroll
    for (int k = 0; k < 8; ++k) {
        int p = tid + (k << 9);
        if (p < nrec) {
            int r = bucketed[p0 + p];
            rec[k] = r;
            rnk[k] = atomicAdd(&cnt[r >> 17], 1);
        } else {
            rec[k] = -1;
        }
    }
    __syncthreads();
    int v = 0;
    if (tid < 128) { v = cnt[tid]; sS[tid] = v; }
    __syncthreads();
    for (int off = 1; off < 128; off <<= 1) {
        int t = (tid >= off && tid < 128) ? sS[tid - off] : 0;
        __syncthreads();
        if (tid < 128) sS[tid] += t;
        __syncthreads();
    }
    if (tid < 128) baseL[tid] = sS[tid] - v;
    __syncthreads();
#pragma unroll
    for (int k = 0; k < 8; ++k)
        if (rec[k] >= 0) lidx[baseL[rec[k] >> 17] + rnk[k]] = rec[k] & 0x1FFFF;
    __syncthreads();

    int g = tid >> 2, l = tid & 3;   // lane l covers bf16 cols 8l..8l+7
    int node = node0 + g;
    if (node >= n) return;
    int cv = cnt[g];
    float dd = rsqrtf((float)(cv + 1));
    int q = baseL[g], q1 = baseL[g] + cv;
    uint4 sw = *(const uint4*)(y2 + (size_t)node * CLS + l * 8);

    float A0 = 0.f, A1 = 0.f, A2 = 0.f, A3 = 0.f, A4 = 0.f, A5 = 0.f, A6 = 0.f, A7 = 0.f;
    float B0 = 0.f, B1 = 0.f, B2 = 0.f, B3 = 0.f, B4 = 0.f, B5 = 0.f, B6 = 0.f, B7 = 0.f;
    for (; q + 1 < q1; q += 2) {
        int s0 = lidx[q], s1 = lidx[q + 1];
        uint4 w0 = *(const uint4*)(y2 + (size_t)s0 * CLS + l * 8);
        uint4 w1 = *(const uint4*)(y2 + (size_t)s1 * CLS + l * 8);
        A0 += bflo(w0.x); A1 += bfhi(w0.x); A2 += bflo(w0.y); A3 += bfhi(w0.y);
        A4 += bflo(w0.z); A5 += bfhi(w0.z); A6 += bflo(w0.w); A7 += bfhi(w0.w);
        B0 += bflo(w1.x); B1 += bfhi(w1.x); B2 += bflo(w1.y); B3 += bfhi(w1.y);
        B4 += bflo(w1.z); B5 += bfhi(w1.z); B6 += bflo(w1.w); B7 += bfhi(w1.w);
    }
    if (q < q1) {
        int s0 = lidx[q];
        uint4 w0 = *(const uint4*)(y2 + (size_t)s0 * CLS + l * 8);
        A0 += bflo(w0.x); A1 += bfhi(w0.x); A2 += bflo(w0.y); A3 += bfhi(w0.y);
        A4 += bflo(w0.z); A5 += bfhi(w0.z); A6 += bflo(w0.w); A7 += bfhi(w0.w);
    }
    A0 += B0; A1 += B1; A2 += B2; A3 += B3;
    A4 += B4; A5 += B5; A6 += B6; A7 += B7;

    float4 bb0 = *(const float4*)(b2 + l * 8);
    float4 bb1 = *(const float4*)(b2 + l * 8 + 4);
    float v0 = (A0 + bflo(sw.x)) * dd + bb0.x;
    float v1 = (A1 + bfhi(sw.x)) * dd + bb0.y;
    float v2 = (A2 + bflo(sw.y)) * dd + bb0.z;
    float v3 = (A3 + bfhi(sw.y)) * dd + bb0.w;
    float v4 = (A4 + bflo(sw.z)) * dd + bb1.x;
    float v5 = (A5 + bfhi(sw.z)) * dd + bb1.y;
    float v6 = (A6 + bflo(sw.w)) * dd + bb1.z;
    float v7 = (A7 + bfhi(sw.w)) * dd + bb1.w;

    float m = fmaxf(fmaxf(fmaxf(v0, v1), fmaxf(v2, v3)), fmaxf(fmaxf(v4, v5), fmaxf(v6, v7)));
    m = fmaxf(m, __shfl_xor(m, 1));
    m = fmaxf(m, __shfl_xor(m, 2));
    float s = __expf(v0 - m) + __expf(v1 - m) + __expf(v2 - m) + __expf(v3 - m) +
              __expf(v4 - m) + __expf(v5 - m) + __expf(v6 - m) + __expf(v7 - m);
    s += __shfl_xor(s, 1);
    s += __shfl_xor(s, 2);
    float ls = m + __logf(s);
    float4 o0, o1;
    o0.x = v0 - ls; o0.y = v1 - ls; o0.z = v2 - ls; o0.w = v3 - ls;
    o1.x = v4 - ls; o1.y = v5 - ls; o1.z = v6 - ls; o1.w = v7 - ls;
    float* op = out + (size_t)node * CLS + l * 8;
    *(float4*)op = o0;
    *(float4*)(op + 4) = o1;
}

extern "C" void kernel_launch(void* const* d_in, const int* in_sizes, int n_in,
                              void* d_out, int out_size, void* d_ws, size_t ws_size,
                              hipStream_t stream) {
    const float* x  = (const float*)d_in[0];
    const int* edge = (const int*)d_in[1];
    const float* W1 = (const float*)d_in[2];
    const float* b1 = (const float*)d_in[3];
    const float* W2 = (const float*)d_in[4];
    const float* b2 = (const float*)d_in[5];
    float* out = (float*)d_out;

    int N = in_sizes[0] / F_IN;
    int E = in_sizes[1] / 2;
    const int* src = edge;
    const int* dst = edge + E;
    int NB = (N + 127) >> 7;   // 782 buckets of 128 nodes

    // workspace layout (no csr/pk arrays needed)
    float* dinv    = (float*)d_ws;                        // N f32
    int* bC        = (int*)(dinv + N);                    // 1024 (delta cursors)
    int* bucketed  = bC + 1024;                           // NB*BCAP
    unsigned char* bufA = (unsigned char*)(bucketed + (size_t)NB * BCAP);  // N*64 B fp8 xW1
    unsigned short* y2  = (unsigned short*)(bufA + (size_t)N * HID);       // N*32 bf16 (normalized)

    // zero delta-cursors (3.1 KB)
    (void)hipMemsetAsync(bC, 0, (size_t)NB * sizeof(int), stream);

    int sB = (E + 4095) / 4096;
    int nstripes16 = (N + 15) >> 4;
    int gB = (nstripes16 + 3) / 4;

    // ---- K1: scatter || gemm1 ----
    k_front<<<sB + gB, 256, 0, stream>>>(src, dst, bC, bucketed, x, W1, bufA, E, NB, N, sB);

    // ---- K2: degree count -> dinv ----
    k_cnt<<<NB, 256, 0, stream>>>(bC, bucketed, dinv, N);

    // ---- K3: LDS-order build + layer-1 gather + W2 MFMA -> y2 ----
    k_g64<<<NB, 512, 0, stream>>>(bC, bucketed, bufA, b1, W2, dinv, y2, N);

    // ---- K4: LDS-order build + layer-2 gather + log_softmax ----
    k_g32<<<NB, 512, 0, stream>>>(bC, bucketed, y2, b2, out, N);
}

// Round 14
// 178.618 us; speedup vs baseline: 6.3985x; 1.0502x over previous
//
#include <hip/hip_runtime.h>

#define F_IN 128
#define HID 64
#define CLS 32
#define BCAP 4096   // per-bucket capacity (128-node buckets, mean 2048 records)

typedef short v8s __attribute__((ext_vector_type(8)));
typedef float f4 __attribute__((ext_vector_type(4)));
typedef float f2 __attribute__((ext_vector_type(2)));

// ---- helpers ----
__device__ __forceinline__ float bflo(unsigned int w) { return __uint_as_float(w << 16); }
__device__ __forceinline__ float bfhi(unsigned int w) { return __uint_as_float(w & 0xFFFF0000u); }
__device__ __forceinline__ unsigned short f2bf(float f) {
    unsigned int u = __float_as_uint(f);
    u += 0x7FFFu + ((u >> 16) & 1u);
    return (unsigned short)(u >> 16);
}
__device__ __forceinline__ unsigned int pack2(float lo, float hi) {
    unsigned int r;
    asm("v_cvt_pk_bf16_f32 %0, %1, %2" : "=v"(r) : "v"(lo), "v"(hi));
    return r;
}
__device__ __forceinline__ unsigned char f2fp8(float v) {
    return (unsigned char)(__builtin_amdgcn_cvt_pk_fp8_f32(v, v, 0, false) & 0xFF);
}

// ============ K1: FRONT (512 thr) = bucket-scatter (8192 edges/blk) || GEMM1 (8 stripes) ====
// Scatter blocks 391->196: halves the per-cursor bC atomic RMW chain (k_front's
// measured critical path; each halving bought ~10us in rounds 3->5).
__global__ __launch_bounds__(512) void k_front(const int* __restrict__ src,
                                               const int* __restrict__ dst,
                                               int* __restrict__ bC,
                                               int* __restrict__ bucketed,
                                               const float* __restrict__ x,
                                               const float* __restrict__ W1,
                                               unsigned char* __restrict__ y,
                                               int E, int nb, int n, int sB) {
    __shared__ union {
        struct { int h[1024]; int chunk[1024]; } sc;
        unsigned short w1[HID * 136];
    } S;
    int tid = threadIdx.x;
    int bid = blockIdx.x;

    if (bid < sB) {
        // ---- bucket scatter: chunk = bid (8192 edges, 16 per thread) ----
        for (int i = tid; i < nb; i += 512) S.sc.h[i] = 0;
        __syncthreads();
        int e0 = bid << 13;
        int myRec[16], myB[16], myRank[16];
#pragma unroll
        for (int k = 0; k < 16; ++k) {
            int e = e0 + k * 512 + tid;
            if (e < E) {
                int d = dst[e];
                myB[k] = d >> 7;
                myRec[k] = src[e] | ((d & 127) << 17);
                myRank[k] = atomicAdd(&S.sc.h[myB[k]], 1);
            } else {
                myB[k] = -1;
            }
        }
        __syncthreads();
        for (int i = tid; i < nb; i += 512)
            S.sc.chunk[i] = S.sc.h[i] ? (i * BCAP + atomicAdd(&bC[i], S.sc.h[i])) : 0;
        __syncthreads();
#pragma unroll
        for (int k = 0; k < 16; ++k)
            if (myB[k] >= 0) bucketed[S.sc.chunk[myB[k]] + myRank[k]] = myRec[k];
    } else {
        // ---- GEMM1: x[N,128] @ W1[128,64] -> fp8 y[N,64] (unnormalized); 8 stripes/blk ----
        for (int i = tid; i < F_IN * HID; i += 512) {
            int k = i >> 6, nn = i & 63;
            S.w1[nn * 136 + k] = f2bf(W1[i]);
        }
        __syncthreads();
        int lane = tid & 63;
        int quad = lane >> 4, c = lane & 15;
        int nstripes = (n + 15) >> 4;
        int stripe = (bid - sB) * 8 + (tid >> 6);
        if (stripe >= nstripes) return;
        int row0 = stripe << 4;

        f4 acc[4] = {};
        union { unsigned int u[4]; v8s v; } au;
#pragma unroll
        for (int ks = 0; ks < 4; ++ks) {
            int k0 = ks * 32 + quad * 8;
            int row = row0 + c;
            if (row >= n) row = n - 1;
            const float* xp = x + (size_t)row * F_IN + k0;
            float4 lo = *(const float4*)xp;
            float4 hi = *(const float4*)(xp + 4);
            au.u[0] = pack2(lo.x, lo.y);
            au.u[1] = pack2(lo.z, lo.w);
            au.u[2] = pack2(hi.x, hi.y);
            au.u[3] = pack2(hi.z, hi.w);
            v8s a = au.v;
#pragma unroll
            for (int nt = 0; nt < 4; ++nt) {
                v8s bb = *(const v8s*)&S.w1[(nt * 16 + c) * 136 + k0];
                acc[nt] = __builtin_amdgcn_mfma_f32_16x16x32_bf16(a, bb, acc[nt], 0, 0, 0);
            }
        }
#pragma unroll
        for (int reg = 0; reg < 4; ++reg) {
            int row = row0 + quad * 4 + reg;
            if (row < n) {
#pragma unroll
                for (int nt = 0; nt < 4; ++nt)
                    y[(size_t)row * HID + nt * 16 + c] = f2fp8(acc[nt][reg]);
            }
        }
    }
}

// ============ K2: per-bucket degree count -> dinv (needed globally by k_g64) ============
__global__ __launch_bounds__(256) void k_cnt(const int* __restrict__ bC,
                                             const int* __restrict__ bucketed,
                                             float* __restrict__ dinv, int n) {
    __shared__ int cnt[128];
    int tid = threadIdx.x, b = blockIdx.x;
    if (tid < 128) cnt[tid] = 0;
    __syncthreads();
    int nrec = bC[b];
    if (nrec > BCAP) nrec = BCAP;
    int p0 = b * BCAP;
    for (int p = tid; p < nrec; p += 256) atomicAdd(&cnt[bucketed[p0 + p] >> 17], 1);
    __syncthreads();
    if (tid < 128) {
        int node = (b << 7) + tid;
        if (node < n) dinv[node] = rsqrtf((float)(cnt[tid] + 1));
    }
}

// ============ K3: per-bucket LDS-order build + gather64 + bias/relu + W2 MFMA -> y2 ====
// 512 thr, block = 1 bucket (128 nodes). Build: cnt->scan->lidx[4096] in LDS.
// Gather: 4 lanes/node, uint4 (16B) fp8 row slices, per-edge dinv[src] FMA.
__global__ __launch_bounds__(512) void k_g64(const int* __restrict__ bC,
                                             const int* __restrict__ bucketed,
                                             const unsigned char* __restrict__ xw8,
                                             const float* __restrict__ b1,
                                             const float* __restrict__ W2,
                                             const float* __restrict__ dinv,
                                             unsigned short* __restrict__ y2, int n) {
    __shared__ int lidx[BCAP];                 // 16 KB
    __shared__ int cnt[128], sS[128], baseL[128];
    __shared__ unsigned short Wt[CLS * 72];    // 4.5 KB
    __shared__ unsigned short Hl[128 * 72];    // 18 KB
    int tid = threadIdx.x, b = blockIdx.x;
    int node0 = b << 7;

    for (int i = tid; i < HID * CLS; i += 512) {
        int k = i >> 5, nn = i & 31;
        Wt[nn * 72 + k] = f2bf(W2[i]);
    }
    if (tid < 128) cnt[tid] = 0;
    __syncthreads();
    int nrec = bC[b];
    if (nrec > BCAP) nrec = BCAP;
    int p0 = b * BCAP;
    int rec[8], rnk[8];
#pragma unroll
    for (int k = 0; k < 8; ++k) {
        int p = tid + (k << 9);
        if (p < nrec) {
            int r = bucketed[p0 + p];
            rec[k] = r;
            rnk[k] = atomicAdd(&cnt[r >> 17], 1);
        } else {
            rec[k] = -1;
        }
    }
    __syncthreads();
    int v = 0;
    if (tid < 128) { v = cnt[tid]; sS[tid] = v; }
    __syncthreads();
    for (int off = 1; off < 128; off <<= 1) {
        int t = (tid >= off && tid < 128) ? sS[tid - off] : 0;
        __syncthreads();
        if (tid < 128) sS[tid] += t;
        __syncthreads();
    }
    if (tid < 128) baseL[tid] = sS[tid] - v;
    __syncthreads();
#pragma unroll
    for (int k = 0; k < 8; ++k)
        if (rec[k] >= 0) lidx[baseL[rec[k] >> 17] + rnk[k]] = rec[k] & 0x1FFFF;
    __syncthreads();

    // ---- gather: group of 4 lanes per node; lane l covers fp8 cols 16l..16l+15 ----
    int g = tid >> 2, l = tid & 3;
    int node = node0 + g;
    if (node < n) {
        int cv = cnt[g];
        float dd = rsqrtf((float)(cv + 1));
        int q = baseL[g], q1 = baseL[g] + cv;
        uint4 sw = *(const uint4*)(xw8 + (size_t)node * HID + l * 16);

        f2 a0 = {0.f, 0.f}, a1 = a0, a2 = a0, a3 = a0, a4 = a0, a5 = a0, a6 = a0, a7 = a0;
        f2 c0 = a0, c1 = a0, c2 = a0, c3 = a0, c4 = a0, c5 = a0, c6 = a0, c7 = a0;
        for (; q + 1 < q1; q += 2) {
            int s0 = lidx[q], s1 = lidx[q + 1];
            float dv0 = dinv[s0], dv1 = dinv[s1];
            uint4 w0 = *(const uint4*)(xw8 + (size_t)s0 * HID + l * 16);
            uint4 w1 = *(const uint4*)(xw8 + (size_t)s1 * HID + l * 16);
            f2 D0 = {dv0, dv0}, D1 = {dv1, dv1};
            a0 += __builtin_amdgcn_cvt_pk_f32_fp8(w0.x, false) * D0;
            a1 += __builtin_amdgcn_cvt_pk_f32_fp8(w0.x, true) * D0;
            a2 += __builtin_amdgcn_cvt_pk_f32_fp8(w0.y, false) * D0;
            a3 += __builtin_amdgcn_cvt_pk_f32_fp8(w0.y, true) * D0;
            a4 += __builtin_amdgcn_cvt_pk_f32_fp8(w0.z, false) * D0;
            a5 += __builtin_amdgcn_cvt_pk_f32_fp8(w0.z, true) * D0;
            a6 += __builtin_amdgcn_cvt_pk_f32_fp8(w0.w, false) * D0;
            a7 += __builtin_amdgcn_cvt_pk_f32_fp8(w0.w, true) * D0;
            c0 += __builtin_amdgcn_cvt_pk_f32_fp8(w1.x, false) * D1;
            c1 += __builtin_amdgcn_cvt_pk_f32_fp8(w1.x, true) * D1;
            c2 += __builtin_amdgcn_cvt_pk_f32_fp8(w1.y, false) * D1;
            c3 += __builtin_amdgcn_cvt_pk_f32_fp8(w1.y, true) * D1;
            c4 += __builtin_amdgcn_cvt_pk_f32_fp8(w1.z, false) * D1;
            c5 += __builtin_amdgcn_cvt_pk_f32_fp8(w1.z, true) * D1;
            c6 += __builtin_amdgcn_cvt_pk_f32_fp8(w1.w, false) * D1;
            c7 += __builtin_amdgcn_cvt_pk_f32_fp8(w1.w, true) * D1;
        }
        if (q < q1) {
            int s0 = lidx[q];
            float dv0 = dinv[s0];
            uint4 w0 = *(const uint4*)(xw8 + (size_t)s0 * HID + l * 16);
            f2 D0 = {dv0, dv0};
            a0 += __builtin_amdgcn_cvt_pk_f32_fp8(w0.x, false) * D0;
            a1 += __builtin_amdgcn_cvt_pk_f32_fp8(w0.x, true) * D0;
            a2 += __builtin_amdgcn_cvt_pk_f32_fp8(w0.y, false) * D0;
            a3 += __builtin_amdgcn_cvt_pk_f32_fp8(w0.y, true) * D0;
            a4 += __builtin_amdgcn_cvt_pk_f32_fp8(w0.z, false) * D0;
            a5 += __builtin_amdgcn_cvt_pk_f32_fp8(w0.z, true) * D0;
            a6 += __builtin_amdgcn_cvt_pk_f32_fp8(w0.w, false) * D0;
            a7 += __builtin_amdgcn_cvt_pk_f32_fp8(w0.w, true) * D0;
        }
        a0 += c0; a1 += c1; a2 += c2; a3 += c3;
        a4 += c4; a5 += c5; a6 += c6; a7 += c7;
        f2 DS = {dd, dd};
        a0 += __builtin_amdgcn_cvt_pk_f32_fp8(sw.x, false) * DS;
        a1 += __builtin_amdgcn_cvt_pk_f32_fp8(sw.x, true) * DS;
        a2 += __builtin_amdgcn_cvt_pk_f32_fp8(sw.y, false) * DS;
        a3 += __builtin_amdgcn_cvt_pk_f32_fp8(sw.y, true) * DS;
        a4 += __builtin_amdgcn_cvt_pk_f32_fp8(sw.z, false) * DS;
        a5 += __builtin_amdgcn_cvt_pk_f32_fp8(sw.z, true) * DS;
        a6 += __builtin_amdgcn_cvt_pk_f32_fp8(sw.w, false) * DS;
        a7 += __builtin_amdgcn_cvt_pk_f32_fp8(sw.w, true) * DS;

        // h = relu(a*dd + b1), 16 cols per lane
        float4 bb0 = *(const float4*)(b1 + l * 16);
        float4 bb1 = *(const float4*)(b1 + l * 16 + 4);
        float4 bb2 = *(const float4*)(b1 + l * 16 + 8);
        float4 bb3 = *(const float4*)(b1 + l * 16 + 12);
        float h0  = fmaxf(a0.x * dd + bb0.x, 0.f), h1  = fmaxf(a0.y * dd + bb0.y, 0.f);
        float h2  = fmaxf(a1.x * dd + bb0.z, 0.f), h3  = fmaxf(a1.y * dd + bb0.w, 0.f);
        float h4  = fmaxf(a2.x * dd + bb1.x, 0.f), h5  = fmaxf(a2.y * dd + bb1.y, 0.f);
        float h6  = fmaxf(a3.x * dd + bb1.z, 0.f), h7  = fmaxf(a3.y * dd + bb1.w, 0.f);
        float h8  = fmaxf(a4.x * dd + bb2.x, 0.f), h9  = fmaxf(a4.y * dd + bb2.y, 0.f);
        float h10 = fmaxf(a5.x * dd + bb2.z, 0.f), h11 = fmaxf(a5.y * dd + bb2.w, 0.f);
        float h12 = fmaxf(a6.x * dd + bb3.x, 0.f), h13 = fmaxf(a6.y * dd + bb3.y, 0.f);
        float h14 = fmaxf(a7.x * dd + bb3.z, 0.f), h15 = fmaxf(a7.y * dd + bb3.w, 0.f);
        uint4* hbp = (uint4*)&Hl[g * 72 + l * 16];
        hbp[0] = make_uint4(pack2(h0, h1), pack2(h2, h3), pack2(h4, h5), pack2(h6, h7));
        hbp[1] = make_uint4(pack2(h8, h9), pack2(h10, h11), pack2(h12, h13), pack2(h14, h15));
    }
    __syncthreads();

    // ---- MFMA: Hb[128][64] @ W2[64][32]: 8 row-tiles x 2 col-tiles, 8 waves x 2 tiles ----
    int wv = tid >> 6, lane = tid & 63, quad = lane >> 4, c = lane & 15;
    int ct = wv & 1;
    int rt0 = wv >> 1;
#pragma unroll
    for (int rr = 0; rr < 2; ++rr) {
        int rt = rt0 + rr * 4;
        f4 acc = {};
#pragma unroll
        for (int ks = 0; ks < 2; ++ks) {
            int k0 = ks * 32 + quad * 8;
            v8s aF = *(const v8s*)&Hl[(rt * 16 + c) * 72 + k0];
            v8s bF = *(const v8s*)&Wt[(ct * 16 + c) * 72 + k0];
            acc = __builtin_amdgcn_mfma_f32_16x16x32_bf16(aF, bF, acc, 0, 0, 0);
        }
#pragma unroll
        for (int reg = 0; reg < 4; ++reg) {
            int rl = rt * 16 + quad * 4 + reg;
            int row = node0 + rl;
            if (row < n) {
                float dd2 = rsqrtf((float)(cnt[rl] + 1));
                y2[(size_t)row * CLS + ct * 16 + c] = f2bf(acc[reg] * dd2);
            }
        }
    }
}

// ============ K4: per-bucket LDS-order build + gather32 + log_softmax ============
__global__ __launch_bounds__(512) void k_g32(const int* __restrict__ bC,
                                             const int* __restrict__ bucketed,
                                             const unsigned short* __restrict__ y2,
                                             const float* __restrict__ b2,
                                             float* __restrict__ out, int n) {
    __shared__ int lidx[BCAP];
    __shared__ int cnt[128], sS[128], baseL[128];
    int tid = threadIdx.x, b = blockIdx.x;
    int node0 = b << 7;
    if (tid < 128) cnt[tid] = 0;
    __syncthreads();
    int nrec = bC[b];
    if (nrec > BCAP) nrec = BCAP;
    int p0 = b * BCAP;
    int rec[8], rnk[8];
#pragma unroll
    for (int k = 0; k < 8; ++k) {
        int p = tid + (k << 9);
        if (p < nrec) {
            int r = bucketed[p0 + p];
            rec[k] = r;
            rnk[k] = atomicAdd(&cnt[r >> 17], 1);
        } else {
            rec[k] = -1;
        }
    }
    __syncthreads();
    int v = 0;
    if (tid < 128) { v = cnt[tid]; sS[tid] = v; }
    __syncthreads();
    for (int off = 1; off < 128; off <<= 1) {
        int t = (tid >= off && tid < 128) ? sS[tid - off] : 0;
        __syncthreads();
        if (tid < 128) sS[tid] += t;
        __syncthreads();
    }
    if (tid < 128) baseL[tid] = sS[tid] - v;
    __syncthreads();
#pragma unroll
    for (int k = 0; k < 8; ++k)
        if (rec[k] >= 0) lidx[baseL[rec[k] >> 17] + rnk[k]] = rec[k] & 0x1FFFF;
    __syncthreads();

    int g = tid >> 2, l = tid & 3;   // lane l covers bf16 cols 8l..8l+7
    int node = node0 + g;
    if (node >= n) return;
    int cv = cnt[g];
    float dd = rsqrtf((float)(cv + 1));
    int q = baseL[g], q1 = baseL[g] + cv;
    uint4 sw = *(const uint4*)(y2 + (size_t)node * CLS + l * 8);

    float A0 = 0.f, A1 = 0.f, A2 = 0.f, A3 = 0.f, A4 = 0.f, A5 = 0.f, A6 = 0.f, A7 = 0.f;
    float B0 = 0.f, B1 = 0.f, B2 = 0.f, B3 = 0.f, B4 = 0.f, B5 = 0.f, B6 = 0.f, B7 = 0.f;
    for (; q + 1 < q1; q += 2) {
        int s0 = lidx[q], s1 = lidx[q + 1];
        uint4 w0 = *(const uint4*)(y2 + (size_t)s0 * CLS + l * 8);
        uint4 w1 = *(const uint4*)(y2 + (size_t)s1 * CLS + l * 8);
        A0 += bflo(w0.x); A1 += bfhi(w0.x); A2 += bflo(w0.y); A3 += bfhi(w0.y);
        A4 += bflo(w0.z); A5 += bfhi(w0.z); A6 += bflo(w0.w); A7 += bfhi(w0.w);
        B0 += bflo(w1.x); B1 += bfhi(w1.x); B2 += bflo(w1.y); B3 += bfhi(w1.y);
        B4 += bflo(w1.z); B5 += bfhi(w1.z); B6 += bflo(w1.w); B7 += bfhi(w1.w);
    }
    if (q < q1) {
        int s0 = lidx[q];
        uint4 w0 = *(const uint4*)(y2 + (size_t)s0 * CLS + l * 8);
        A0 += bflo(w0.x); A1 += bfhi(w0.x); A2 += bflo(w0.y); A3 += bfhi(w0.y);
        A4 += bflo(w0.z); A5 += bfhi(w0.z); A6 += bflo(w0.w); A7 += bfhi(w0.w);
    }
    A0 += B0; A1 += B1; A2 += B2; A3 += B3;
    A4 += B4; A5 += B5; A6 += B6; A7 += B7;

    float4 bb0 = *(const float4*)(b2 + l * 8);
    float4 bb1 = *(const float4*)(b2 + l * 8 + 4);
    float v0 = (A0 + bflo(sw.x)) * dd + bb0.x;
    float v1 = (A1 + bfhi(sw.x)) * dd + bb0.y;
    float v2 = (A2 + bflo(sw.y)) * dd + bb0.z;
    float v3 = (A3 + bfhi(sw.y)) * dd + bb0.w;
    float v4 = (A4 + bflo(sw.z)) * dd + bb1.x;
    float v5 = (A5 + bfhi(sw.z)) * dd + bb1.y;
    float v6 = (A6 + bflo(sw.w)) * dd + bb1.z;
    float v7 = (A7 + bfhi(sw.w)) * dd + bb1.w;

    float m = fmaxf(fmaxf(fmaxf(v0, v1), fmaxf(v2, v3)), fmaxf(fmaxf(v4, v5), fmaxf(v6, v7)));
    m = fmaxf(m, __shfl_xor(m, 1));
    m = fmaxf(m, __shfl_xor(m, 2));
    float s = __expf(v0 - m) + __expf(v1 - m) + __expf(v2 - m) + __expf(v3 - m) +
              __expf(v4 - m) + __expf(v5 - m) + __expf(v6 - m) + __expf(v7 - m);
    s += __shfl_xor(s, 1);
    s += __shfl_xor(s, 2);
    float ls = m + __logf(s);
    float4 o0, o1;
    o0.x = v0 - ls; o0.y = v1 - ls; o0.z = v2 - ls; o0.w = v3 - ls;
    o1.x = v4 - ls; o1.y = v5 - ls; o1.z = v6 - ls; o1.w = v7 - ls;
    float* op = out + (size_t)node * CLS + l * 8;
    *(float4*)op = o0;
    *(float4*)(op + 4) = o1;
}

extern "C" void kernel_launch(void* const* d_in, const int* in_sizes, int n_in,
                              void* d_out, int out_size, void* d_ws, size_t ws_size,
                              hipStream_t stream) {
    const float* x  = (const float*)d_in[0];
    const int* edge = (const int*)d_in[1];
    const float* W1 = (const float*)d_in[2];
    const float* b1 = (const float*)d_in[3];
    const float* W2 = (const float*)d_in[4];
    const float* b2 = (const float*)d_in[5];
    float* out = (float*)d_out;

    int N = in_sizes[0] / F_IN;
    int E = in_sizes[1] / 2;
    const int* src = edge;
    const int* dst = edge + E;
    int NB = (N + 127) >> 7;   // 782 buckets of 128 nodes

    // workspace layout (no csr/pk arrays)
    float* dinv    = (float*)d_ws;                        // N f32
    int* bC        = (int*)(dinv + N);                    // 1024 (delta cursors)
    int* bucketed  = bC + 1024;                           // NB*BCAP
    unsigned char* bufA = (unsigned char*)(bucketed + (size_t)NB * BCAP);  // N*64 B fp8 xW1
    unsigned short* y2  = (unsigned short*)(bufA + (size_t)N * HID);       // N*32 bf16 (normalized)

    // zero delta-cursors (3.1 KB)
    (void)hipMemsetAsync(bC, 0, (size_t)NB * sizeof(int), stream);

    int sB = (E + 8191) / 8192;               // 196 scatter blocks (8192-edge chunks)
    int nstripes16 = (N + 15) >> 4;
    int gB = (nstripes16 + 7) / 8;            // 782 gemm1 blocks (8 stripes each)

    // ---- K1: scatter || gemm1 (512 threads, static split) ----
    k_front<<<sB + gB, 512, 0, stream>>>(src, dst, bC, bucketed, x, W1, bufA, E, NB, N, sB);

    // ---- K2: degree count -> dinv ----
    k_cnt<<<NB, 256, 0, stream>>>(bC, bucketed, dinv, N);

    // ---- K3: LDS-order build + layer-1 gather + W2 MFMA -> y2 ----
    k_g64<<<NB, 512, 0, stream>>>(bC, bucketed, bufA, b1, W2, dinv, y2, N);

    // ---- K4: LDS-order build + layer-2 gather + log_softmax ----
    k_g32<<<NB, 512, 0, stream>>>(bC, bucketed, y2, b2, out, N);
}